// Round 3
// baseline (355.839 us; speedup 1.0000x reference)
//
#include <hip/hip_runtime.h>
#include <hip/hip_bf16.h>

typedef __bf16 bf16;
typedef __bf16 bf16x8 __attribute__((ext_vector_type(8)));
typedef float f32x4 __attribute__((ext_vector_type(4)));

#define B_ 16
#define N_ 1024
#define F_ 512

// dtype-agnostic scalar read: element i of p as float
__device__ __forceinline__ float rdv(const void* p, size_t i, int f32) {
  return f32 ? ((const float*)p)[i] : (float)((const bf16*)p)[i];
}

// Detect input dtype from W1's raw 32-bit words. For bf16 data the low 16 bits
// are a real weight (|v| < 0.25 -> bf16 exp field <= ~125). For fp32 data the
// low 16 bits are mantissa bits (~uniform) -> ~49% have exp field >= 130.
__global__ void k_detect(const unsigned* __restrict__ w, int* __restrict__ flag) {
  __shared__ int red[256];
  const int t = threadIdx.x;
  int c = 0;
  for (int i = t; i < 4096; i += 256) {
    unsigned e = (w[i] >> 7) & 0xFFu;  // exponent field of low-half-as-bf16
    c += (e >= 130u) ? 1 : 0;
  }
  red[t] = c;
  __syncthreads();
  for (int s = 128; s > 0; s >>= 1) {
    if (t < s) red[t] += red[t + s];
    __syncthreads();
  }
  if (t == 0) flag[0] = (red[0] > 100) ? 1 : 0;  // 1 = fp32 inputs
}

// bc[z*512 + j] = float(b_z[j])
__global__ void k_bias(const void* b1, const void* b2, const void* b3,
                       const int* __restrict__ flag, float* __restrict__ bc) {
  const int j = blockIdx.x * 256 + threadIdx.x;  // 0..1535
  const int f = flag[0];
  const void* src = (j < 512) ? b1 : (j < 1024 ? b2 : b3);
  bc[j] = rdv(src, (size_t)(j & 511), f);
}

// xc[i] = bf16(x[i])  (internal bf16 copy of batch_graph)
__global__ void k_xc(const void* x, const int* __restrict__ flag, bf16* __restrict__ xc) {
  const size_t i = (size_t)blockIdx.x * 256 + threadIdx.x;
  xc[i] = (bf16)rdv(x, i, flag[0]);
}

// cs[b][j] = sum_i adj[b][i][j]  (column sums; fp32 accumulate)
__global__ void k_colsum(const void* adj, const int* __restrict__ flag,
                         float* __restrict__ cs) {
  __shared__ float red[256];
  const int t = threadIdx.x;
  const int f = flag[0];
  const int jj = t & 63, ic = t >> 6;
  const int b = blockIdx.y;
  const int j0 = blockIdx.x * 64;
  const size_t base = (size_t)b * N_ * N_ + (size_t)(ic * 256) * N_ + j0 + jj;
  float s = 0.f;
#pragma unroll 8
  for (int i = 0; i < 256; ++i) s += rdv(adj, base + (size_t)i * N_, f);
  red[t] = s;
  __syncthreads();
  if (t < 64) cs[b * N_ + j0 + t] = red[t] + red[t + 64] + red[t + 128] + red[t + 192];
}

// anorm[b][i][j] = bf16( r_i * adj[b][j][i] * r_j ),  r = cs^-1/2 (0 if cs<=0)
__global__ void k_anorm(const void* adj, const int* __restrict__ flag,
                        const float* __restrict__ cs, bf16* __restrict__ anorm) {
  __shared__ float tile[32][33];
  const int tx = threadIdx.x, ty = threadIdx.y;
  const int f = flag[0];
  const int b = blockIdx.z, i0 = blockIdx.y * 32, j0 = blockIdx.x * 32;
  const size_t sb = (size_t)b * N_ * N_;
#pragma unroll
  for (int s = 0; s < 4; ++s) {
    int jj = ty + 8 * s;
    tile[jj][tx] = rdv(adj, sb + (size_t)(j0 + jj) * N_ + i0 + tx, f);
  }
  float cj = cs[b * N_ + j0 + tx];
  float rj = cj > 0.f ? rsqrtf(cj) : 0.f;
  __syncthreads();
  bf16* dst = anorm + sb;
#pragma unroll
  for (int s = 0; s < 4; ++s) {
    int ii = ty + 8 * s;
    float ci = cs[b * N_ + i0 + ii];
    float ri = ci > 0.f ? rsqrtf(ci) : 0.f;
    dst[(size_t)(i0 + ii) * N_ + j0 + tx] = (bf16)(ri * tile[tx][ii] * rj);
  }
}

// Wt[z][f][k] = bf16( W_z[k][f] )   (512x512 transposes, z = 0..2)
__global__ void k_wt(const void* W1, const void* W2, const void* W3,
                     const int* __restrict__ flag, bf16* __restrict__ Wt) {
  __shared__ float tile[32][33];
  const int tx = threadIdx.x, ty = threadIdx.y;
  const int f = flag[0];
  const int z = blockIdx.z;
  const void* W = (z == 0) ? W1 : ((z == 1) ? W2 : W3);
  bf16* dst = Wt + (size_t)z * F_ * F_;
  const int k0 = blockIdx.y * 32, f0 = blockIdx.x * 32;
#pragma unroll
  for (int s = 0; s < 4; ++s)
    tile[ty + 8 * s][tx] = rdv(W, (size_t)(k0 + ty + 8 * s) * F_ + f0 + tx, f);
  __syncthreads();
#pragma unroll
  for (int s = 0; s < 4; ++s)
    dst[(size_t)(f0 + ty + 8 * s) * F_ + k0 + tx] = (bf16)tile[tx][ty + 8 * s];
}

// C[M][Nc] = A[M][K] * Bt[Nc][K]^T (+bias, optional ReLU).
// A, Bt internal bf16. Output bf16 (OUTDYN=0) or flag-selected fp32/bf16 (OUTDYN=1).
// 128x128 tile, BK=32, 4 waves (2x2), each wave 4x4 of 16x16x32 MFMA.
template <int BIAS, int RELU, int OUTDYN>
__global__ __launch_bounds__(256)
void k_gemm_bt(const bf16* __restrict__ A, const bf16* __restrict__ Bt,
               const float* __restrict__ bias, void* __restrict__ C,
               const int* __restrict__ flag,
               int Nc, int K, long sA, long sB, long sC) {
  __shared__ __align__(16) bf16 As[128 * 32];
  __shared__ __align__(16) bf16 Bs[128 * 32];
  const int tid = threadIdx.x;
  const int wid = tid >> 6, lane = tid & 63;
  const int wm = wid >> 1, wn = wid & 1;
  const int quad = lane >> 4, l16 = lane & 15;
  const int srow = tid >> 2;       // 0..63
  const int scol = (tid & 3) * 8;  // 0,8,16,24

  const bf16* gA = A + (size_t)blockIdx.z * sA + (size_t)blockIdx.y * 128 * K;
  const bf16* gB = Bt + (size_t)blockIdx.z * sB + (size_t)blockIdx.x * 128 * K;

  f32x4 acc[4][4];
#pragma unroll
  for (int i = 0; i < 4; ++i)
#pragma unroll
    for (int j = 0; j < 4; ++j) acc[i][j] = (f32x4){0.f, 0.f, 0.f, 0.f};

  for (int k0 = 0; k0 < K; k0 += 32) {
    bf16x8 a0 = *(const bf16x8*)&gA[(size_t)srow * K + k0 + scol];
    bf16x8 a1 = *(const bf16x8*)&gA[(size_t)(64 + srow) * K + k0 + scol];
    bf16x8 b0 = *(const bf16x8*)&gB[(size_t)srow * K + k0 + scol];
    bf16x8 b1 = *(const bf16x8*)&gB[(size_t)(64 + srow) * K + k0 + scol];
    __syncthreads();
    *(bf16x8*)&As[srow * 32 + scol] = a0;
    *(bf16x8*)&As[(64 + srow) * 32 + scol] = a1;
    *(bf16x8*)&Bs[srow * 32 + scol] = b0;
    *(bf16x8*)&Bs[(64 + srow) * 32 + scol] = b1;
    __syncthreads();

    bf16x8 af[4], bfv[4];
#pragma unroll
    for (int tm = 0; tm < 4; ++tm)
      af[tm] = *(const bf16x8*)&As[(wm * 64 + tm * 16 + l16) * 32 + quad * 8];
#pragma unroll
    for (int tn = 0; tn < 4; ++tn)
      bfv[tn] = *(const bf16x8*)&Bs[(wn * 64 + tn * 16 + l16) * 32 + quad * 8];
#pragma unroll
    for (int tm = 0; tm < 4; ++tm)
#pragma unroll
      for (int tn = 0; tn < 4; ++tn)
        acc[tm][tn] =
            __builtin_amdgcn_mfma_f32_16x16x32_bf16(af[tm], bfv[tn], acc[tm][tn], 0, 0, 0);
  }

  // epilogue: C/D layout col = lane&15, row = quad*4 + reg  [verified m89/m91]
  const int of32 = OUTDYN ? flag[0] : 0;
  const size_t cb = (size_t)blockIdx.z * sC;
  const int mb = blockIdx.y * 128 + wm * 64;
  const int nb = blockIdx.x * 128 + wn * 64;
#pragma unroll
  for (int tn = 0; tn < 4; ++tn) {
    const int n = nb + tn * 16 + l16;
    float bv = 0.f;
    if (BIAS) bv = bias[n];
#pragma unroll
    for (int tm = 0; tm < 4; ++tm) {
      const int m0 = mb + tm * 16 + quad * 4;
#pragma unroll
      for (int r = 0; r < 4; ++r) {
        float v = acc[tm][tn][r] + bv;
        if (RELU) v = v > 0.f ? v : 0.f;
        const size_t idx = cb + (size_t)(m0 + r) * Nc + n;
        if (OUTDYN && of32)
          ((float*)C)[idx] = v;
        else
          ((bf16*)C)[idx] = (bf16)v;
      }
    }
  }
}

extern "C" void kernel_launch(void* const* d_in, const int* in_sizes, int n_in,
                              void* d_out, int out_size, void* d_ws, size_t ws_size,
                              hipStream_t stream) {
  // workspace layout (~49.6 MB): cs | flag | bc | anorm | Wt | Zt
  char* ws = (char*)d_ws;
  float* cs   = (float*)ws;                       // 64 KB
  int*  flag  = (int*)(ws + 65536);               // 256 B
  float* bc   = (float*)(ws + 65792);             // 6 KB   [3][512] fp32 bias
  bf16* anorm = (bf16*)(ws + 71936);              // 32 MB  [B][N][N]
  bf16* Wt    = (bf16*)(ws + 71936 + 33554432);   // 1.5 MB [3][F][F]
  bf16* Zt    = (bf16*)(ws + 71936 + 33554432 + 3 * F_ * F_ * 2);  // 16 MB [B][F][N]
  // d_out doubles as internal bf16 activation scratch (Xc / Xw), 16 MB;
  // the final GEMM overwrites it with the real output (fp32 or bf16 per flag).
  bf16* Xc = (bf16*)d_out;

  const long sW = 0;
  const long sX = (long)N_ * F_;
  const long sZ = (long)F_ * N_;
  const long sAn = (long)N_ * N_;

  k_detect<<<1, 256, 0, stream>>>((const unsigned*)d_in[2], flag);
  k_bias<<<6, 256, 0, stream>>>(d_in[3], d_in[5], d_in[7], flag, bc);
  k_xc<<<(B_ * N_ * F_) / 256, 256, 0, stream>>>(d_in[0], flag, Xc);
  k_colsum<<<dim3(N_ / 64, B_), 256, 0, stream>>>(d_in[1], flag, cs);
  k_anorm<<<dim3(N_ / 32, N_ / 32, B_), dim3(32, 8), 0, stream>>>(d_in[1], flag, cs, anorm);
  k_wt<<<dim3(F_ / 32, F_ / 32, 3), dim3(32, 8), 0, stream>>>(d_in[2], d_in[4], d_in[6], flag, Wt);

  dim3 g1(N_ / 128, F_ / 128, B_);  // Zt = Wt_z * X^T : M=F(512), Nc=N(1024), K=F(512)
  dim3 g2(F_ / 128, N_ / 128, B_);  // X' = anorm * Zt^T : M=N(1024), Nc=F(512), K=N(1024)

  // layer 1
  k_gemm_bt<0, 0, 0><<<g1, 256, 0, stream>>>(Wt,               Xc, nullptr,   Zt, flag, N_, F_, sW, sX, sZ);
  k_gemm_bt<1, 1, 0><<<g2, 256, 0, stream>>>(anorm,            Zt, bc,        Xc, flag, F_, N_, sAn, sZ, sX);
  // layer 2
  k_gemm_bt<0, 0, 0><<<g1, 256, 0, stream>>>(Wt + F_ * F_,     Xc, nullptr,   Zt, flag, N_, F_, sW, sX, sZ);
  k_gemm_bt<1, 1, 0><<<g2, 256, 0, stream>>>(anorm,            Zt, bc + 512,  Xc, flag, F_, N_, sAn, sZ, sX);
  // layer 3
  k_gemm_bt<0, 0, 0><<<g1, 256, 0, stream>>>(Wt + 2 * F_ * F_, Xc, nullptr,   Zt, flag, N_, F_, sW, sX, sZ);
  k_gemm_bt<1, 0, 1><<<g2, 256, 0, stream>>>(anorm,            Zt, bc + 1024, d_out, flag, F_, N_, sAn, sZ, sX);
}

// Round 4
// 332.549 us; speedup vs baseline: 1.0700x; 1.0700x over previous
//
#include <hip/hip_runtime.h>
#include <hip/hip_bf16.h>

typedef __bf16 bf16;
typedef __bf16 bf16x8 __attribute__((ext_vector_type(8)));
typedef float f32x4 __attribute__((ext_vector_type(4)));

#define B_ 16
#define N_ 1024
#define F_ 512

__device__ __forceinline__ float rdv(const void* p, size_t i, int f32) {
  return f32 ? ((const float*)p)[i] : (float)((const bf16*)p)[i];
}

// async global->LDS, 16B per lane; LDS dest = wave-uniform base + lane*16
__device__ __forceinline__ void gld16(const bf16* g, bf16* l) {
  __builtin_amdgcn_global_load_lds(
      (const __attribute__((address_space(1))) unsigned int*)g,
      (__attribute__((address_space(3))) unsigned int*)l, 16, 0, 0);
}

// Detect input dtype from W1's raw words (bf16 pair: low half is a small
// weight, exp<=~125; fp32: bits7..14 are mantissa bits, ~49% >= 130).
__global__ void k_detect(const unsigned* __restrict__ w, int* __restrict__ flag) {
  __shared__ int red[256];
  const int t = threadIdx.x;
  int c = 0;
  for (int i = t; i < 4096; i += 256) c += (((w[i] >> 7) & 0xFFu) >= 130u) ? 1 : 0;
  red[t] = c;
  __syncthreads();
  for (int s = 128; s > 0; s >>= 1) {
    if (t < s) red[t] += red[t + s];
    __syncthreads();
  }
  if (t == 0) flag[0] = (red[0] > 100) ? 1 : 0;  // 1 = fp32 inputs
}

// Fused small prep: bias convert (blocks 0..5), W transposes (6..773),
// X -> bf16 copy Xc (774..8965, 4 elems/thread).
__global__ void k_prep(const void* b1, const void* b2, const void* b3,
                       const void* W1, const void* W2, const void* W3,
                       const void* X, const int* __restrict__ flag,
                       float* __restrict__ bc, bf16* __restrict__ Wt,
                       bf16* __restrict__ xc) {
  __shared__ float tile[32][33];
  const int bid = blockIdx.x;
  const int t = threadIdx.x;
  const int f = flag[0];
  if (bid < 6) {
    const int j = bid * 256 + t;  // 0..1535
    const void* src = (j < 512) ? b1 : (j < 1024 ? b2 : b3);
    bc[j] = rdv(src, (size_t)(j & 511), f);
  } else if (bid < 774) {
    const int bid2 = bid - 6;
    const int z = bid2 >> 8, ti = bid2 & 255;
    const int f0 = (ti & 15) * 32, k0 = (ti >> 4) * 32;
    const int tx = t & 31, ty = t >> 5;
    const void* W = (z == 0) ? W1 : ((z == 1) ? W2 : W3);
    bf16* dst = Wt + (size_t)z * F_ * F_;
#pragma unroll
    for (int s = 0; s < 4; ++s)
      tile[ty + 8 * s][tx] = rdv(W, (size_t)(k0 + ty + 8 * s) * F_ + f0 + tx, f);
    __syncthreads();
#pragma unroll
    for (int s = 0; s < 4; ++s)
      dst[(size_t)(f0 + ty + 8 * s) * F_ + k0 + tx] = (bf16)tile[tx][ty + 8 * s];
  } else {
    const size_t i4 = ((size_t)(bid - 774) * 256 + t) * 4;
    if (f) {
      f32x4 v = *(const f32x4*)((const float*)X + i4);
      bf16 o[4] = {(bf16)v[0], (bf16)v[1], (bf16)v[2], (bf16)v[3]};
      *(ulong1*)&xc[i4] = *(ulong1*)o;  // 8B store
    } else {
      *(ulong1*)&xc[i4] = *(const ulong1*)((const bf16*)X + i4);  // bitcopy
    }
  }
}

// Split-K column sums: csp[z][b][j] = sum_{i in z-th 256-row slice} adj[b][i][j]
__global__ void k_colsum(const void* adj, const int* __restrict__ flag,
                         float* __restrict__ csp) {
  __shared__ float red[256];
  const int t = threadIdx.x;
  const int jj = t & 63, ic = t >> 6;  // 64 cols x 4 row-subchunks
  const int b = blockIdx.y, z = blockIdx.z;
  const int j0 = blockIdx.x * 64;
  const size_t base = (size_t)b * N_ * N_ + (size_t)(z * 256 + ic * 64) * N_ + j0 + jj;
  float s = 0.f;
  if (flag[0]) {
    const float* p = (const float*)adj + base;
#pragma unroll 16
    for (int i = 0; i < 64; ++i) s += p[(size_t)i * N_];
  } else {
    const bf16* p = (const bf16*)adj + base;
#pragma unroll 16
    for (int i = 0; i < 64; ++i) s += (float)p[(size_t)i * N_];
  }
  red[t] = s;
  __syncthreads();
  if (t < 64)
    csp[((size_t)z * B_ + b) * N_ + j0 + t] = red[t] + red[t + 64] + red[t + 128] + red[t + 192];
}

__device__ __forceinline__ float csum(const float* csp, int b, int j) {
  float c = 0.f;
#pragma unroll
  for (int z = 0; z < 4; ++z) c += csp[((size_t)z * B_ + b) * N_ + j];
  return c;
}

// anorm[b][i][j] = bf16( r_i * adj[b][j][i] * r_j ),  r = colsum^-1/2 (0 if <=0)
__global__ void k_anorm(const void* adj, const int* __restrict__ flag,
                        const float* __restrict__ csp, bf16* __restrict__ anorm) {
  __shared__ float tile[32][33];
  const int tx = threadIdx.x, ty = threadIdx.y;
  const int f = flag[0];
  const int b = blockIdx.z, i0 = blockIdx.y * 32, j0 = blockIdx.x * 32;
  const size_t sb = (size_t)b * N_ * N_;
#pragma unroll
  for (int s = 0; s < 4; ++s) {
    int jj = ty + 8 * s;
    tile[jj][tx] = rdv(adj, sb + (size_t)(j0 + jj) * N_ + i0 + tx, f);
  }
  float cj = csum(csp, b, j0 + tx);
  float rj = cj > 0.f ? rsqrtf(cj) : 0.f;
  __syncthreads();
  bf16* dst = anorm + sb;
#pragma unroll
  for (int s = 0; s < 4; ++s) {
    int ii = ty + 8 * s;
    float ci = csum(csp, b, i0 + ii);
    float ri = ci > 0.f ? rsqrtf(ci) : 0.f;
    dst[(size_t)(i0 + ii) * N_ + j0 + tx] = (bf16)(ri * tile[tx][ii] * rj);
  }
}

// C[M][Nc] = A[M][K] * Bt[Nc][K]^T (+bias, optional ReLU).
// 128x128 tile, BK=32, 4 waves (2x2), 4x4 x mfma_f32_16x16x32_bf16 per wave.
// Staging via global_load_lds width=16 (m97 ladder step 3).
template <int BIAS, int RELU, int OUTDYN>
__global__ __launch_bounds__(256)
void k_gemm_bt(const bf16* __restrict__ A, const bf16* __restrict__ Bt,
               const float* __restrict__ bias, void* __restrict__ C,
               const int* __restrict__ flag,
               int Nc, int K, long sA, long sB, long sC) {
  __shared__ __align__(16) bf16 As[128 * 32];
  __shared__ __align__(16) bf16 Bs[128 * 32];
  const int tid = threadIdx.x;
  const int wid = tid >> 6, lane = tid & 63;
  const int wm = wid >> 1, wn = wid & 1;
  const int quad = lane >> 4, l16 = lane & 15;
  const int srow = lane >> 2;       // 0..15 (16 rows per wave-issue)
  const int scol = (lane & 3) * 8;  // 0,8,16,24

  const bf16* gA = A + (size_t)blockIdx.z * sA + (size_t)blockIdx.y * 128 * K;
  const bf16* gB = Bt + (size_t)blockIdx.z * sB + (size_t)blockIdx.x * 128 * K;

  f32x4 acc[4][4];
#pragma unroll
  for (int i = 0; i < 4; ++i)
#pragma unroll
    for (int j = 0; j < 4; ++j) acc[i][j] = (f32x4){0.f, 0.f, 0.f, 0.f};

  for (int k0 = 0; k0 < K; k0 += 32) {
#pragma unroll
    for (int half = 0; half < 2; ++half) {
      const int r = half * 64 + wid * 16;  // wave-uniform LDS row base
      gld16(gA + (size_t)(r + srow) * K + k0 + scol, &As[r * 32]);
      gld16(gB + (size_t)(r + srow) * K + k0 + scol, &Bs[r * 32]);
    }
    __syncthreads();  // barrier drains vmcnt -> LDS tiles complete

    bf16x8 af[4], bfv[4];
#pragma unroll
    for (int tm = 0; tm < 4; ++tm)
      af[tm] = *(const bf16x8*)&As[(wm * 64 + tm * 16 + l16) * 32 + quad * 8];
#pragma unroll
    for (int tn = 0; tn < 4; ++tn)
      bfv[tn] = *(const bf16x8*)&Bs[(wn * 64 + tn * 16 + l16) * 32 + quad * 8];
#pragma unroll
    for (int tm = 0; tm < 4; ++tm)
#pragma unroll
      for (int tn = 0; tn < 4; ++tn)
        acc[tm][tn] =
            __builtin_amdgcn_mfma_f32_16x16x32_bf16(af[tm], bfv[tn], acc[tm][tn], 0, 0, 0);
    __syncthreads();  // protect LDS before next stage
  }

  // epilogue: C/D layout col = lane&15, row = quad*4 + reg  [m89/m91]
  const int of32 = OUTDYN ? flag[0] : 0;
  const size_t cb = (size_t)blockIdx.z * sC;
  const int mb = blockIdx.y * 128 + wm * 64;
  const int nb = blockIdx.x * 128 + wn * 64;
#pragma unroll
  for (int tn = 0; tn < 4; ++tn) {
    const int n = nb + tn * 16 + l16;
    float bv = 0.f;
    if (BIAS) bv = bias[n];
#pragma unroll
    for (int tm = 0; tm < 4; ++tm) {
      const int m0 = mb + tm * 16 + quad * 4;
#pragma unroll
      for (int r = 0; r < 4; ++r) {
        float v = acc[tm][tn][r] + bv;
        if (RELU) v = v > 0.f ? v : 0.f;
        const size_t idx = cb + (size_t)(m0 + r) * Nc + n;
        if (OUTDYN && of32)
          ((float*)C)[idx] = v;
        else
          ((bf16*)C)[idx] = (bf16)v;
      }
    }
  }
}

extern "C" void kernel_launch(void* const* d_in, const int* in_sizes, int n_in,
                              void* d_out, int out_size, void* d_ws, size_t ws_size,
                              hipStream_t stream) {
  // ws layout: csp(256KB) | flag(256B) | bc(6KB+pad) | anorm(32MB) | Wt(1.5MB) | Zt(16MB)
  char* ws = (char*)d_ws;
  float* csp  = (float*)ws;                        // 256 KB [4][B][N]
  int*  flag  = (int*)(ws + 262144);               // 256 B
  float* bc   = (float*)(ws + 262400);             // 6 KB [3][512]
  bf16* anorm = (bf16*)(ws + 270592);              // 32 MB [B][N][N]
  bf16* Wt    = (bf16*)(ws + 270592 + 33554432);   // 1.5 MB [3][F][F]
  bf16* Zt    = (bf16*)(ws + 270592 + 33554432 + 3 * F_ * F_ * 2);  // 16 MB [B][F][N]
  bf16* Xc = (bf16*)d_out;  // d_out doubles as bf16 activation scratch (16.8 MB)

  const long sW = 0;
  const long sX = (long)N_ * F_;
  const long sZ = (long)F_ * N_;
  const long sAn = (long)N_ * N_;

  k_detect<<<1, 256, 0, stream>>>((const unsigned*)d_in[2], flag);
  k_prep<<<774 + (B_ * N_ * F_) / 1024, 256, 0, stream>>>(
      d_in[3], d_in[5], d_in[7], d_in[2], d_in[4], d_in[6], d_in[0], flag, bc, Wt, Xc);
  k_colsum<<<dim3(N_ / 64, B_, 4), 256, 0, stream>>>(d_in[1], flag, csp);
  k_anorm<<<dim3(N_ / 32, N_ / 32, B_), dim3(32, 8), 0, stream>>>(d_in[1], flag, csp, anorm);

  dim3 g1(N_ / 128, F_ / 128, B_);  // Zt = Wt_z * X^T : M=F, Nc=N, K=F
  dim3 g2(F_ / 128, N_ / 128, B_);  // X' = anorm * Zt^T : M=N, Nc=F, K=N

  // layer 1
  k_gemm_bt<0, 0, 0><<<g1, 256, 0, stream>>>(Wt,               Xc, nullptr,   Zt, flag, N_, F_, sW, sX, sZ);
  k_gemm_bt<1, 1, 0><<<g2, 256, 0, stream>>>(anorm,            Zt, bc,        Xc, flag, F_, N_, sAn, sZ, sX);
  // layer 2
  k_gemm_bt<0, 0, 0><<<g1, 256, 0, stream>>>(Wt + F_ * F_,     Xc, nullptr,   Zt, flag, N_, F_, sW, sX, sZ);
  k_gemm_bt<1, 1, 0><<<g2, 256, 0, stream>>>(anorm,            Zt, bc + 512,  Xc, flag, F_, N_, sAn, sZ, sX);
  // layer 3
  k_gemm_bt<0, 0, 0><<<g1, 256, 0, stream>>>(Wt + 2 * F_ * F_, Xc, nullptr,   Zt, flag, N_, F_, sW, sX, sZ);
  k_gemm_bt<1, 0, 1><<<g2, 256, 0, stream>>>(anorm,            Zt, bc + 1024, d_out, flag, F_, N_, sAn, sZ, sX);
}

// Round 5
// 309.574 us; speedup vs baseline: 1.1494x; 1.0742x over previous
//
#include <hip/hip_runtime.h>
#include <hip/hip_bf16.h>

typedef __bf16 bf16;
typedef __bf16 bf16x8 __attribute__((ext_vector_type(8)));
typedef float f32x4 __attribute__((ext_vector_type(4)));

#define B_ 16
#define N_ 1024
#define F_ 512

__device__ __forceinline__ float rdv(const void* p, size_t i, int f32) {
  return f32 ? ((const float*)p)[i] : (float)((const bf16*)p)[i];
}

// async global->LDS, 16B per lane; LDS dest = wave-uniform base + lane*16
__device__ __forceinline__ void gld16(const bf16* g, bf16* l) {
  __builtin_amdgcn_global_load_lds(
      (const __attribute__((address_space(1))) unsigned int*)g,
      (__attribute__((address_space(3))) unsigned int*)l, 16, 0, 0);
}

// Detect input dtype from W1's raw words (bf16 pair: low half is a small
// weight, exp<=~125; fp32: bits7..14 are mantissa bits, ~49% >= 130).
__global__ void k_detect(const unsigned* __restrict__ w, int* __restrict__ flag) {
  __shared__ int red[256];
  const int t = threadIdx.x;
  int c = 0;
  for (int i = t; i < 4096; i += 256) c += (((w[i] >> 7) & 0xFFu) >= 130u) ? 1 : 0;
  red[t] = c;
  __syncthreads();
  for (int s = 128; s > 0; s >>= 1) {
    if (t < s) red[t] += red[t + s];
    __syncthreads();
  }
  if (t == 0) flag[0] = (red[0] > 100) ? 1 : 0;  // 1 = fp32 inputs
}

// Fused small prep: bias convert (blocks 0..5), W transposes (6..773),
// X -> bf16 copy Xc (774.., 4 elems/thread).
__global__ void k_prep(const void* b1, const void* b2, const void* b3,
                       const void* W1, const void* W2, const void* W3,
                       const void* X, const int* __restrict__ flag,
                       float* __restrict__ bc, bf16* __restrict__ Wt,
                       bf16* __restrict__ xc) {
  __shared__ float tile[32][33];
  const int bid = blockIdx.x;
  const int t = threadIdx.x;
  const int f = flag[0];
  if (bid < 6) {
    const int j = bid * 256 + t;  // 0..1535
    const void* src = (j < 512) ? b1 : (j < 1024 ? b2 : b3);
    bc[j] = rdv(src, (size_t)(j & 511), f);
  } else if (bid < 774) {
    const int bid2 = bid - 6;
    const int z = bid2 >> 8, ti = bid2 & 255;
    const int f0 = (ti & 15) * 32, k0 = (ti >> 4) * 32;
    const int tx = t & 31, ty = t >> 5;
    const void* W = (z == 0) ? W1 : ((z == 1) ? W2 : W3);
    bf16* dst = Wt + (size_t)z * F_ * F_;
#pragma unroll
    for (int s = 0; s < 4; ++s)
      tile[ty + 8 * s][tx] = rdv(W, (size_t)(k0 + ty + 8 * s) * F_ + f0 + tx, f);
    __syncthreads();
#pragma unroll
    for (int s = 0; s < 4; ++s)
      dst[(size_t)(f0 + ty + 8 * s) * F_ + k0 + tx] = (bf16)tile[tx][ty + 8 * s];
  } else {
    const size_t i4 = ((size_t)(bid - 774) * 256 + t) * 4;
    if (f) {
      f32x4 v = *(const f32x4*)((const float*)X + i4);
      bf16 o[4] = {(bf16)v[0], (bf16)v[1], (bf16)v[2], (bf16)v[3]};
      *(ulong1*)&xc[i4] = *(ulong1*)o;  // 8B store
    } else {
      *(ulong1*)&xc[i4] = *(const ulong1*)((const bf16*)X + i4);  // bitcopy
    }
  }
}

// Split-K column sums: csp[z][b][j] = sum_{i in z-th 256-row slice} adj[b][i][j]
__global__ void k_colsum(const void* adj, const int* __restrict__ flag,
                         float* __restrict__ csp) {
  __shared__ float red[256];
  const int t = threadIdx.x;
  const int jj = t & 63, ic = t >> 6;
  const int b = blockIdx.y, z = blockIdx.z;
  const int j0 = blockIdx.x * 64;
  const size_t base = (size_t)b * N_ * N_ + (size_t)(z * 256 + ic * 64) * N_ + j0 + jj;
  float s = 0.f;
  if (flag[0]) {
    const float* p = (const float*)adj + base;
#pragma unroll 16
    for (int i = 0; i < 64; ++i) s += p[(size_t)i * N_];
  } else {
    const bf16* p = (const bf16*)adj + base;
#pragma unroll 16
    for (int i = 0; i < 64; ++i) s += (float)p[(size_t)i * N_];
  }
  red[t] = s;
  __syncthreads();
  if (t < 64)
    csp[((size_t)z * B_ + b) * N_ + j0 + t] = red[t] + red[t + 64] + red[t + 128] + red[t + 192];
}

__device__ __forceinline__ float csum(const float* csp, int b, int j) {
  float c = 0.f;
#pragma unroll
  for (int z = 0; z < 4; ++z) c += csp[((size_t)z * B_ + b) * N_ + j];
  return c;
}

// anorm[b][i][j] = bf16( r_i * adj[b][j][i] * r_j ),  r = colsum^-1/2 (0 if <=0)
__global__ void k_anorm(const void* adj, const int* __restrict__ flag,
                        const float* __restrict__ csp, bf16* __restrict__ anorm) {
  __shared__ float tile[32][33];
  const int tx = threadIdx.x, ty = threadIdx.y;
  const int f = flag[0];
  const int b = blockIdx.z, i0 = blockIdx.y * 32, j0 = blockIdx.x * 32;
  const size_t sb = (size_t)b * N_ * N_;
#pragma unroll
  for (int s = 0; s < 4; ++s) {
    int jj = ty + 8 * s;
    tile[jj][tx] = rdv(adj, sb + (size_t)(j0 + jj) * N_ + i0 + tx, f);
  }
  float cj = csum(csp, b, j0 + tx);
  float rj = cj > 0.f ? rsqrtf(cj) : 0.f;
  __syncthreads();
  bf16* dst = anorm + sb;
#pragma unroll
  for (int s = 0; s < 4; ++s) {
    int ii = ty + 8 * s;
    float ci = csum(csp, b, i0 + ii);
    float ri = ci > 0.f ? rsqrtf(ci) : 0.f;
    dst[(size_t)(i0 + ii) * N_ + j0 + tx] = (bf16)(ri * tile[tx][ii] * rj);
  }
}

// C[M][Nc] = A[M][K] * Bt[Nc][K]^T (+bias, optional ReLU).
// 128x128 tile, BK=64, 4 waves (2x2), 2x(4x4) mfma_f32_16x16x32_bf16 per wave.
// Staging via global_load_lds w=16 with XOR chunk swizzle:
//   LDS row r, 16B-chunk c_l holds global chunk c_l ^ (r&7)  -> fragment
//   ds_read_b128 stays bank-balanced (8 words/bank) at 128B row stride.
// Epilogue (OUTDYN=0): acc -> per-wave padded LDS tile -> 16B coalesced stores.
template <int BIAS, int RELU, int OUTDYN>
__global__ __launch_bounds__(256)
void k_gemm_bt(const bf16* __restrict__ A, const bf16* __restrict__ Bt,
               const float* __restrict__ bias, void* __restrict__ C,
               const int* __restrict__ flag,
               int Nc, int K, long sA, long sB, long sC) {
  __shared__ __align__(16) char smem[36864];
  bf16* As = (bf16*)smem;            // [128][64] elems
  bf16* Bs = (bf16*)(smem + 16384);  // [128][64]
  const int tid = threadIdx.x;
  const int wid = tid >> 6, lane = tid & 63;
  const int wm = wid >> 1, wn = wid & 1;
  const int quad = lane >> 4, l16 = lane & 15;
  const int rl = lane >> 3;                 // 0..7 staging row within 8-row issue
  const int cg8 = ((lane & 7) ^ rl) * 8;    // swizzled global col offset (elems)
  const int h = l16 & 7;                    // fragment-read swizzle key

  const bf16* gA = A + (size_t)blockIdx.z * sA + (size_t)blockIdx.y * 128 * K;
  const bf16* gB = Bt + (size_t)blockIdx.z * sB + (size_t)blockIdx.x * 128 * K;

  f32x4 acc[4][4];
#pragma unroll
  for (int i = 0; i < 4; ++i)
#pragma unroll
    for (int j = 0; j < 4; ++j) acc[i][j] = (f32x4){0.f, 0.f, 0.f, 0.f};

  for (int k0 = 0; k0 < K; k0 += 64) {
#pragma unroll
    for (int i = 0; i < 4; ++i) {
      const int r0 = wid * 32 + i * 8;  // wave-uniform LDS row base
      gld16(gA + (size_t)(r0 + rl) * K + k0 + cg8, &As[r0 * 64]);
      gld16(gB + (size_t)(r0 + rl) * K + k0 + cg8, &Bs[r0 * 64]);
    }
    __syncthreads();  // drains vmcnt -> both tiles complete

#pragma unroll
    for (int s = 0; s < 2; ++s) {
      bf16x8 af[4], bfv[4];
#pragma unroll
      for (int tm = 0; tm < 4; ++tm)
        af[tm] = *(const bf16x8*)&As[(wm * 64 + tm * 16 + l16) * 64 +
                                     (((quad + 4 * s) ^ h) * 8)];
#pragma unroll
      for (int tn = 0; tn < 4; ++tn)
        bfv[tn] = *(const bf16x8*)&Bs[(wn * 64 + tn * 16 + l16) * 64 +
                                      (((quad + 4 * s) ^ h) * 8)];
#pragma unroll
      for (int tm = 0; tm < 4; ++tm)
#pragma unroll
        for (int tn = 0; tn < 4; ++tn)
          acc[tm][tn] =
              __builtin_amdgcn_mfma_f32_16x16x32_bf16(af[tm], bfv[tn], acc[tm][tn], 0, 0, 0);
    }
    __syncthreads();  // protect LDS before next stage
  }

  // C/D layout: col = lane&15, row = quad*4 + reg  [m89/m91]
  const size_t cb = (size_t)blockIdx.z * sC;
  const int mb_w = blockIdx.y * 128 + wm * 64;
  const int nb_w = blockIdx.x * 128 + wn * 64;

  if (OUTDYN) {
    // final layer: scalar stores, fp32 or bf16 per runtime flag
    const int of32 = flag[0];
#pragma unroll
    for (int tn = 0; tn < 4; ++tn) {
      const int n = nb_w + tn * 16 + l16;
      float bv = BIAS ? bias[n] : 0.f;
#pragma unroll
      for (int tm = 0; tm < 4; ++tm) {
        const int m0 = mb_w + tm * 16 + quad * 4;
#pragma unroll
        for (int r = 0; r < 4; ++r) {
          float v = acc[tm][tn][r] + bv;
          if (RELU) v = v > 0.f ? v : 0.f;
          const size_t idx = cb + (size_t)(m0 + r) * Nc + n;
          if (of32) ((float*)C)[idx] = v;
          else      ((bf16*)C)[idx] = (bf16)v;
        }
      }
    }
  } else {
    // repack through per-wave LDS tile [64][72] (16B-aligned rows), then
    // 16B coalesced stores (128B contiguous per 8-lane row group).
    bf16* W = (bf16*)smem + wid * (64 * 72);
#pragma unroll
    for (int tn = 0; tn < 4; ++tn) {
      const int n = nb_w + tn * 16 + l16;
      float bv = BIAS ? bias[n] : 0.f;
#pragma unroll
      for (int tm = 0; tm < 4; ++tm) {
#pragma unroll
        for (int r = 0; r < 4; ++r) {
          float v = acc[tm][tn][r] + bv;
          if (RELU) v = v > 0.f ? v : 0.f;
          W[(tm * 16 + quad * 4 + r) * 72 + tn * 16 + l16] = (bf16)v;
        }
      }
    }
    // wave-private tile: no barrier needed, lgkmcnt ordering suffices
    bf16* gC = (bf16*)C + cb;
#pragma unroll
    for (int i = 0; i < 8; ++i) {
      const int row = i * 8 + rl;
      bf16x8 v = *(const bf16x8*)&W[row * 72 + (lane & 7) * 8];
      *(bf16x8*)&gC[(size_t)(mb_w + row) * Nc + nb_w + (lane & 7) * 8] = v;
    }
  }
}

extern "C" void kernel_launch(void* const* d_in, const int* in_sizes, int n_in,
                              void* d_out, int out_size, void* d_ws, size_t ws_size,
                              hipStream_t stream) {
  // ws layout: csp(256KB) | flag(256B) | bc(6KB+pad) | anorm(32MB) | Wt(1.5MB) | Zt(16MB)
  char* ws = (char*)d_ws;
  float* csp  = (float*)ws;                        // 256 KB [4][B][N]
  int*  flag  = (int*)(ws + 262144);               // 256 B
  float* bc   = (float*)(ws + 262400);             // 6 KB [3][512]
  bf16* anorm = (bf16*)(ws + 270592);              // 32 MB [B][N][N]
  bf16* Wt    = (bf16*)(ws + 270592 + 33554432);   // 1.5 MB [3][F][F]
  bf16* Zt    = (bf16*)(ws + 270592 + 33554432 + 3 * F_ * F_ * 2);  // 16 MB [B][F][N]
  bf16* Xc = (bf16*)d_out;  // d_out doubles as bf16 activation scratch (16.8 MB)

  const long sW = 0;
  const long sX = (long)N_ * F_;
  const long sZ = (long)F_ * N_;
  const long sAn = (long)N_ * N_;

  k_detect<<<1, 256, 0, stream>>>((const unsigned*)d_in[2], flag);
  k_prep<<<774 + (B_ * N_ * F_) / 1024, 256, 0, stream>>>(
      d_in[3], d_in[5], d_in[7], d_in[2], d_in[4], d_in[6], d_in[0], flag, bc, Wt, Xc);
  k_colsum<<<dim3(N_ / 64, B_, 4), 256, 0, stream>>>(d_in[1], flag, csp);
  k_anorm<<<dim3(N_ / 32, N_ / 32, B_), dim3(32, 8), 0, stream>>>(d_in[1], flag, csp, anorm);

  dim3 g1(N_ / 128, F_ / 128, B_);  // Zt = Wt_z * X^T : M=F, Nc=N, K=F
  dim3 g2(F_ / 128, N_ / 128, B_);  // X' = anorm * Zt^T : M=N, Nc=F, K=N

  // layer 1
  k_gemm_bt<0, 0, 0><<<g1, 256, 0, stream>>>(Wt,               Xc, nullptr,   Zt, flag, N_, F_, sW, sX, sZ);
  k_gemm_bt<1, 1, 0><<<g2, 256, 0, stream>>>(anorm,            Zt, bc,        Xc, flag, F_, N_, sAn, sZ, sX);
  // layer 2
  k_gemm_bt<0, 0, 0><<<g1, 256, 0, stream>>>(Wt + F_ * F_,     Xc, nullptr,   Zt, flag, N_, F_, sW, sX, sZ);
  k_gemm_bt<1, 1, 0><<<g2, 256, 0, stream>>>(anorm,            Zt, bc + 512,  Xc, flag, F_, N_, sAn, sZ, sX);
  // layer 3
  k_gemm_bt<0, 0, 0><<<g1, 256, 0, stream>>>(Wt + 2 * F_ * F_, Xc, nullptr,   Zt, flag, N_, F_, sW, sX, sZ);
  k_gemm_bt<1, 0, 1><<<g2, 256, 0, stream>>>(anorm,            Zt, bc + 1024, d_out, flag, F_, N_, sAn, sZ, sX);
}

// Round 6
// 296.230 us; speedup vs baseline: 1.2012x; 1.0450x over previous
//
#include <hip/hip_runtime.h>
#include <hip/hip_bf16.h>

typedef __bf16 bf16;
typedef __bf16 bf16x4 __attribute__((ext_vector_type(4)));
typedef __bf16 bf16x8 __attribute__((ext_vector_type(8)));
typedef float f32x4 __attribute__((ext_vector_type(4)));

#define B_ 16
#define N_ 1024
#define F_ 512

__device__ __forceinline__ float rdv(const void* p, size_t i, int f32) {
  return f32 ? ((const float*)p)[i] : (float)((const bf16*)p)[i];
}

// async global->LDS, 16B per lane; LDS dest = wave-uniform base + lane*16
__device__ __forceinline__ void gld16(const bf16* g, bf16* l) {
  __builtin_amdgcn_global_load_lds(
      (const __attribute__((address_space(1))) unsigned int*)g,
      (__attribute__((address_space(3))) unsigned int*)l, 16, 0, 0);
}

// Detect input dtype from W1's raw words (bf16 pair: low half is a small
// weight, exp<=~125; fp32: bits7..14 are mantissa bits, ~49% >= 130).
__global__ void k_detect(const unsigned* __restrict__ w, int* __restrict__ flag) {
  __shared__ int red[256];
  const int t = threadIdx.x;
  int c = 0;
  for (int i = t; i < 4096; i += 256) c += (((w[i] >> 7) & 0xFFu) >= 130u) ? 1 : 0;
  red[t] = c;
  __syncthreads();
  for (int s = 128; s > 0; s >>= 1) {
    if (t < s) red[t] += red[t + s];
    __syncthreads();
  }
  if (t == 0) flag[0] = (red[0] > 100) ? 1 : 0;  // 1 = fp32 inputs
}

// Fused small prep: bias convert (blocks 0..5), W transposes (6..773),
// X -> bf16 copy Xc (774.., 4 elems/thread).
__global__ void k_prep(const void* b1, const void* b2, const void* b3,
                       const void* W1, const void* W2, const void* W3,
                       const void* X, const int* __restrict__ flag,
                       float* __restrict__ bc, bf16* __restrict__ Wt,
                       bf16* __restrict__ xc) {
  __shared__ float tile[32][33];
  const int bid = blockIdx.x;
  const int t = threadIdx.x;
  const int f = flag[0];
  if (bid < 6) {
    const int j = bid * 256 + t;  // 0..1535
    const void* src = (j < 512) ? b1 : (j < 1024 ? b2 : b3);
    bc[j] = rdv(src, (size_t)(j & 511), f);
  } else if (bid < 774) {
    const int bid2 = bid - 6;
    const int z = bid2 >> 8, ti = bid2 & 255;
    const int f0 = (ti & 15) * 32, k0 = (ti >> 4) * 32;
    const int tx = t & 31, ty = t >> 5;
    const void* W = (z == 0) ? W1 : ((z == 1) ? W2 : W3);
    bf16* dst = Wt + (size_t)z * F_ * F_;
#pragma unroll
    for (int s = 0; s < 4; ++s)
      tile[ty + 8 * s][tx] = rdv(W, (size_t)(k0 + ty + 8 * s) * F_ + f0 + tx, f);
    __syncthreads();
#pragma unroll
    for (int s = 0; s < 4; ++s)
      dst[(size_t)(f0 + ty + 8 * s) * F_ + k0 + tx] = (bf16)tile[tx][ty + 8 * s];
  } else {
    const size_t i4 = ((size_t)(bid - 774) * 256 + t) * 4;
    if (f) {
      f32x4 v = *(const f32x4*)((const float*)X + i4);
      bf16 o[4] = {(bf16)v[0], (bf16)v[1], (bf16)v[2], (bf16)v[3]};
      *(ulong1*)&xc[i4] = *(ulong1*)o;  // 8B store
    } else {
      *(ulong1*)&xc[i4] = *(const ulong1*)((const bf16*)X + i4);  // bitcopy
    }
  }
}

// Split-K column sums: csp[z][b][j] = sum_{i in z-th 256-row slice} adj[b][i][j]
__global__ void k_colsum(const void* adj, const int* __restrict__ flag,
                         float* __restrict__ csp) {
  __shared__ float red[256];
  const int t = threadIdx.x;
  const int jj = t & 63, ic = t >> 6;
  const int b = blockIdx.y, z = blockIdx.z;
  const int j0 = blockIdx.x * 64;
  const size_t base = (size_t)b * N_ * N_ + (size_t)(z * 256 + ic * 64) * N_ + j0 + jj;
  float s = 0.f;
  if (flag[0]) {
    const float* p = (const float*)adj + base;
#pragma unroll 16
    for (int i = 0; i < 64; ++i) s += p[(size_t)i * N_];
  } else {
    const bf16* p = (const bf16*)adj + base;
#pragma unroll 16
    for (int i = 0; i < 64; ++i) s += (float)p[(size_t)i * N_];
  }
  red[t] = s;
  __syncthreads();
  if (t < 64)
    csp[((size_t)z * B_ + b) * N_ + j0 + t] = red[t] + red[t + 64] + red[t + 128] + red[t + 192];
}

__device__ __forceinline__ float csum(const float* csp, int b, int j) {
  float c = 0.f;
#pragma unroll
  for (int z = 0; z < 4; ++z) c += csp[((size_t)z * B_ + b) * N_ + j];
  return c;
}

// anorm[b][i][j] = bf16( r_i * adj[b][j][i] * r_j ),  r = colsum^-1/2 (0 if <=0)
// 64x64 tile, 16x16 threads, vectorized 16B loads / 8B stores.
__global__ void k_anorm(const void* adj, const int* __restrict__ flag,
                        const float* __restrict__ csp, bf16* __restrict__ anorm) {
  __shared__ float tile[64][65];
  __shared__ float rI[64], rJ[64];
  const int tx = threadIdx.x, ty = threadIdx.y;  // 16,16
  const int t = ty * 16 + tx;
  const int b = blockIdx.z, i0 = blockIdx.y * 64, j0 = blockIdx.x * 64;
  const size_t sb = (size_t)b * N_ * N_;
  if (t < 64) {
    float c = csum(csp, b, i0 + t);
    rI[t] = c > 0.f ? rsqrtf(c) : 0.f;
  } else if (t < 128) {
    float c = csum(csp, b, j0 + (t - 64));
    rJ[t - 64] = c > 0.f ? rsqrtf(c) : 0.f;
  }
  if (flag[0]) {
    const float* src = (const float*)adj + sb;
#pragma unroll
    for (int s = 0; s < 4; ++s) {
      const int jj = ty + 16 * s;
      f32x4 v = *(const f32x4*)&src[(size_t)(j0 + jj) * N_ + i0 + 4 * tx];
#pragma unroll
      for (int u = 0; u < 4; ++u) tile[jj][4 * tx + u] = v[u];
    }
  } else {
    const bf16* src = (const bf16*)adj + sb;
#pragma unroll
    for (int s = 0; s < 4; ++s) {
      const int jj = ty + 16 * s;
      bf16x4 v = *(const bf16x4*)&src[(size_t)(j0 + jj) * N_ + i0 + 4 * tx];
#pragma unroll
      for (int u = 0; u < 4; ++u) tile[jj][4 * tx + u] = (float)v[u];
    }
  }
  __syncthreads();
  bf16* dst = anorm + sb;
#pragma unroll
  for (int s = 0; s < 4; ++s) {
    const int ii = ty + 16 * s;
    const float ri = rI[ii];
    bf16x4 o;
#pragma unroll
    for (int u = 0; u < 4; ++u)
      o[u] = (bf16)(ri * tile[4 * tx + u][ii] * rJ[4 * tx + u]);
    *(bf16x4*)&dst[(size_t)(i0 + ii) * N_ + j0 + 4 * tx] = o;
  }
}

// C[M][Nc] = A[M][K] * Bt[Nc][K]^T (+bias, optional ReLU).
// 128x128 tile, BK=64, double-buffered LDS, software pipeline with raw
// s_barrier + fine-grained vmcnt (prefetch stays in flight across barrier).
// Staging via global_load_lds w=16 with XOR chunk swizzle (round-5 verified).
// Epilogue (OUTDYN=0): acc -> per-wave padded LDS tile -> 16B coalesced stores.
template <int BIAS, int RELU, int OUTDYN>
__global__ __launch_bounds__(256)
void k_gemm_bt(const bf16* __restrict__ A, const bf16* __restrict__ Bt,
               const float* __restrict__ bias, void* __restrict__ C,
               const int* __restrict__ flag,
               int Nc, int K, long sA, long sB, long sC) {
  __shared__ __align__(16) char smem[65536];  // 2 x (As 16KB + Bs 16KB)
  const int tid = threadIdx.x;
  const int wid = tid >> 6, lane = tid & 63;
  const int wm = wid >> 1, wn = wid & 1;
  const int quad = lane >> 4, l16 = lane & 15;
  const int rl = lane >> 3;               // 0..7 staging row within 8-row issue
  const int cg8 = ((lane & 7) ^ rl) * 8;  // swizzled global col offset (elems)
  const int h = l16 & 7;                  // fragment-read swizzle key

  const bf16* gA = A + (size_t)blockIdx.z * sA + (size_t)blockIdx.y * 128 * K;
  const bf16* gB = Bt + (size_t)blockIdx.z * sB + (size_t)blockIdx.x * 128 * K;

  f32x4 acc[4][4];
#pragma unroll
  for (int i = 0; i < 4; ++i)
#pragma unroll
    for (int j = 0; j < 4; ++j) acc[i][j] = (f32x4){0.f, 0.f, 0.f, 0.f};

  // stage tile (8 gld16 per lane) into buffer d
  auto stage = [&](int d, int k0) {
    bf16* As = (bf16*)(smem + d * 32768);
    bf16* Bs = (bf16*)(smem + d * 32768 + 16384);
#pragma unroll
    for (int i = 0; i < 4; ++i) {
      const int r0 = wid * 32 + i * 8;  // wave-uniform LDS row base
      gld16(gA + (size_t)(r0 + rl) * K + k0 + cg8, &As[r0 * 64]);
      gld16(gB + (size_t)(r0 + rl) * K + k0 + cg8, &Bs[r0 * 64]);
    }
  };

  stage(0, 0);
  for (int k0 = 0; k0 < K; k0 += 64) {
    const int cur = (k0 >> 6) & 1;
    if (k0 + 64 < K) {
      stage(1 - cur, k0 + 64);
      // wait only for tile-cur's 8 loads; prefetch (8 newest) stays in flight
      asm volatile("s_waitcnt vmcnt(8)\n\ts_barrier" ::: "memory");
    } else {
      asm volatile("s_waitcnt vmcnt(0)\n\ts_barrier" ::: "memory");
    }
    const bf16* As = (const bf16*)(smem + cur * 32768);
    const bf16* Bs = (const bf16*)(smem + cur * 32768 + 16384);
#pragma unroll
    for (int s = 0; s < 2; ++s) {
      bf16x8 af[4], bfv[4];
#pragma unroll
      for (int tm = 0; tm < 4; ++tm)
        af[tm] = *(const bf16x8*)&As[(wm * 64 + tm * 16 + l16) * 64 +
                                     (((quad + 4 * s) ^ h) * 8)];
#pragma unroll
      for (int tn = 0; tn < 4; ++tn)
        bfv[tn] = *(const bf16x8*)&Bs[(wn * 64 + tn * 16 + l16) * 64 +
                                      (((quad + 4 * s) ^ h) * 8)];
#pragma unroll
      for (int tm = 0; tm < 4; ++tm)
#pragma unroll
        for (int tn = 0; tn < 4; ++tn)
          acc[tm][tn] =
              __builtin_amdgcn_mfma_f32_16x16x32_bf16(af[tm], bfv[tn], acc[tm][tn], 0, 0, 0);
    }
    // end-of-iter: execution barrier only (ds_reads of cur complete via data
    // deps; next iteration overwrites buf cur only after all waves pass here)
    asm volatile("s_barrier" ::: "memory");
  }

  // C/D layout: col = lane&15, row = quad*4 + reg  [m89/m91]
  const size_t cb = (size_t)blockIdx.z * sC;
  const int mb_w = blockIdx.y * 128 + wm * 64;
  const int nb_w = blockIdx.x * 128 + wn * 64;

  if (OUTDYN) {
    const int of32 = flag[0];
#pragma unroll
    for (int tn = 0; tn < 4; ++tn) {
      const int n = nb_w + tn * 16 + l16;
      float bv = BIAS ? bias[n] : 0.f;
#pragma unroll
      for (int tm = 0; tm < 4; ++tm) {
        const int m0 = mb_w + tm * 16 + quad * 4;
#pragma unroll
        for (int r = 0; r < 4; ++r) {
          float v = acc[tm][tn][r] + bv;
          if (RELU) v = v > 0.f ? v : 0.f;
          const size_t idx = cb + (size_t)(m0 + r) * Nc + n;
          if (of32) ((float*)C)[idx] = v;
          else      ((bf16*)C)[idx] = (bf16)v;
        }
      }
    }
  } else {
    // repack through per-wave LDS tile [64][72], then 16B coalesced stores
    bf16* W = (bf16*)smem + wid * (64 * 72);
#pragma unroll
    for (int tn = 0; tn < 4; ++tn) {
      const int n = nb_w + tn * 16 + l16;
      float bv = BIAS ? bias[n] : 0.f;
#pragma unroll
      for (int tm = 0; tm < 4; ++tm) {
#pragma unroll
        for (int r = 0; r < 4; ++r) {
          float v = acc[tm][tn][r] + bv;
          if (RELU) v = v > 0.f ? v : 0.f;
          W[(tm * 16 + quad * 4 + r) * 72 + tn * 16 + l16] = (bf16)v;
        }
      }
    }
    bf16* gC = (bf16*)C + cb;
#pragma unroll
    for (int i = 0; i < 8; ++i) {
      const int row = i * 8 + rl;
      bf16x8 v = *(const bf16x8*)&W[row * 72 + (lane & 7) * 8];
      *(bf16x8*)&gC[(size_t)(mb_w + row) * Nc + nb_w + (lane & 7) * 8] = v;
    }
  }
}

extern "C" void kernel_launch(void* const* d_in, const int* in_sizes, int n_in,
                              void* d_out, int out_size, void* d_ws, size_t ws_size,
                              hipStream_t stream) {
  // ws layout: csp(256KB) | flag(256B) | bc(6KB+pad) | anorm(32MB) | Wt(1.5MB) | Zt(16MB)
  char* ws = (char*)d_ws;
  float* csp  = (float*)ws;                        // 256 KB [4][B][N]
  int*  flag  = (int*)(ws + 262144);               // 256 B
  float* bc   = (float*)(ws + 262400);             // 6 KB [3][512]
  bf16* anorm = (bf16*)(ws + 270592);              // 32 MB [B][N][N]
  bf16* Wt    = (bf16*)(ws + 270592 + 33554432);   // 1.5 MB [3][F][F]
  bf16* Zt    = (bf16*)(ws + 270592 + 33554432 + 3 * F_ * F_ * 2);  // 16 MB [B][F][N]
  bf16* Xc = (bf16*)d_out;  // d_out doubles as bf16 activation scratch (16.8 MB)

  const long sW = 0;
  const long sX = (long)N_ * F_;
  const long sZ = (long)F_ * N_;
  const long sAn = (long)N_ * N_;

  k_detect<<<1, 256, 0, stream>>>((const unsigned*)d_in[2], flag);
  k_prep<<<774 + (B_ * N_ * F_) / 1024, 256, 0, stream>>>(
      d_in[3], d_in[5], d_in[7], d_in[2], d_in[4], d_in[6], d_in[0], flag, bc, Wt, Xc);
  k_colsum<<<dim3(N_ / 64, B_, 4), 256, 0, stream>>>(d_in[1], flag, csp);
  k_anorm<<<dim3(N_ / 64, N_ / 64, B_), dim3(16, 16), 0, stream>>>(d_in[1], flag, csp, anorm);

  dim3 g1(N_ / 128, F_ / 128, B_);  // Zt = Wt_z * X^T : M=F, Nc=N, K=F
  dim3 g2(F_ / 128, N_ / 128, B_);  // X' = anorm * Zt^T : M=N, Nc=F, K=N

  // layer 1
  k_gemm_bt<0, 0, 0><<<g1, 256, 0, stream>>>(Wt,               Xc, nullptr,   Zt, flag, N_, F_, sW, sX, sZ);
  k_gemm_bt<1, 1, 0><<<g2, 256, 0, stream>>>(anorm,            Zt, bc,        Xc, flag, F_, N_, sAn, sZ, sX);
  // layer 2
  k_gemm_bt<0, 0, 0><<<g1, 256, 0, stream>>>(Wt + F_ * F_,     Xc, nullptr,   Zt, flag, N_, F_, sW, sX, sZ);
  k_gemm_bt<1, 1, 0><<<g2, 256, 0, stream>>>(anorm,            Zt, bc + 512,  Xc, flag, F_, N_, sAn, sZ, sX);
  // layer 3
  k_gemm_bt<0, 0, 0><<<g1, 256, 0, stream>>>(Wt + 2 * F_ * F_, Xc, nullptr,   Zt, flag, N_, F_, sW, sX, sZ);
  k_gemm_bt<1, 0, 1><<<g2, 256, 0, stream>>>(anorm,            Zt, bc + 1024, d_out, flag, F_, N_, sAn, sZ, sX);
}

// Round 7
// 259.643 us; speedup vs baseline: 1.3705x; 1.1409x over previous
//
#include <hip/hip_runtime.h>
#include <hip/hip_bf16.h>

typedef __bf16 bf16;
typedef __bf16 bf16x4 __attribute__((ext_vector_type(4)));
typedef __bf16 bf16x8 __attribute__((ext_vector_type(8)));
typedef float f32x4 __attribute__((ext_vector_type(4)));

#define B_ 16
#define N_ 1024
#define F_ 512

__device__ __forceinline__ float rdv(const void* p, size_t i, int f32) {
  return f32 ? ((const float*)p)[i] : (float)((const bf16*)p)[i];
}

// async global->LDS, 16B per lane; LDS dest = wave-uniform base + lane*16
__device__ __forceinline__ void gld16(const bf16* g, bf16* l) {
  __builtin_amdgcn_global_load_lds(
      (const __attribute__((address_space(1))) unsigned int*)g,
      (__attribute__((address_space(3))) unsigned int*)l, 16, 0, 0);
}

// Detect input dtype from W1's raw words (bf16 pair: low half is a small
// weight, exp<=~125; fp32: bits7..14 are mantissa bits, ~49% >= 130).
__global__ void k_detect(const unsigned* __restrict__ w, int* __restrict__ flag) {
  __shared__ int red[256];
  const int t = threadIdx.x;
  int c = 0;
  for (int i = t; i < 4096; i += 256) c += (((w[i] >> 7) & 0xFFu) >= 130u) ? 1 : 0;
  red[t] = c;
  __syncthreads();
  for (int s = 128; s > 0; s >>= 1) {
    if (t < s) red[t] += red[t + s];
    __syncthreads();
  }
  if (t == 0) flag[0] = (red[0] > 100) ? 1 : 0;  // 1 = fp32 inputs
}

// Fused small prep: bias convert (blocks 0..5), W transposes (6..773),
// X -> bf16 copy Xc (774.., 4 elems/thread).
__global__ void k_prep(const void* b1, const void* b2, const void* b3,
                       const void* W1, const void* W2, const void* W3,
                       const void* X, const int* __restrict__ flag,
                       float* __restrict__ bc, bf16* __restrict__ Wt,
                       bf16* __restrict__ xc) {
  __shared__ float tile[32][33];
  const int bid = blockIdx.x;
  const int t = threadIdx.x;
  const int f = flag[0];
  if (bid < 6) {
    const int j = bid * 256 + t;  // 0..1535
    const void* src = (j < 512) ? b1 : (j < 1024 ? b2 : b3);
    bc[j] = rdv(src, (size_t)(j & 511), f);
  } else if (bid < 774) {
    const int bid2 = bid - 6;
    const int z = bid2 >> 8, ti = bid2 & 255;
    const int f0 = (ti & 15) * 32, k0 = (ti >> 4) * 32;
    const int tx = t & 31, ty = t >> 5;
    const void* W = (z == 0) ? W1 : ((z == 1) ? W2 : W3);
    bf16* dst = Wt + (size_t)z * F_ * F_;
#pragma unroll
    for (int s = 0; s < 4; ++s)
      tile[ty + 8 * s][tx] = rdv(W, (size_t)(k0 + ty + 8 * s) * F_ + f0 + tx, f);
    __syncthreads();
#pragma unroll
    for (int s = 0; s < 4; ++s)
      dst[(size_t)(f0 + ty + 8 * s) * F_ + k0 + tx] = (bf16)tile[tx][ty + 8 * s];
  } else {
    const size_t i4 = ((size_t)(bid - 774) * 256 + t) * 4;
    if (f) {
      f32x4 v = *(const f32x4*)((const float*)X + i4);
      bf16 o[4] = {(bf16)v[0], (bf16)v[1], (bf16)v[2], (bf16)v[3]};
      *(ulong1*)&xc[i4] = *(ulong1*)o;  // 8B store
    } else {
      *(ulong1*)&xc[i4] = *(const ulong1*)((const bf16*)X + i4);  // bitcopy
    }
  }
}

// Fused transpose + column-sum partials:
//   adjT[b][i][j] = bf16(adj[b][j][i])
//   csp[j0/64][b][i] = sum_{j in [j0,j0+64)} adj[b][j][i]   (fp32, no atomics)
__global__ void k_tran(const void* adj, const int* __restrict__ flag,
                       bf16* __restrict__ adjT, float* __restrict__ csp) {
  __shared__ float tile[64][65];
  __shared__ float red[4][64];
  const int tx = threadIdx.x, ty = threadIdx.y;  // 16,16
  const int t = ty * 16 + tx;
  const int b = blockIdx.z, i0 = blockIdx.y * 64, j0 = blockIdx.x * 64;
  const size_t sb = (size_t)b * N_ * N_;
  if (flag[0]) {
    const float* src = (const float*)adj + sb;
#pragma unroll
    for (int s = 0; s < 4; ++s) {
      const int jj = ty + 16 * s;
      f32x4 v = *(const f32x4*)&src[(size_t)(j0 + jj) * N_ + i0 + 4 * tx];
#pragma unroll
      for (int u = 0; u < 4; ++u) tile[jj][4 * tx + u] = v[u];
    }
  } else {
    const bf16* src = (const bf16*)adj + sb;
#pragma unroll
    for (int s = 0; s < 4; ++s) {
      const int jj = ty + 16 * s;
      bf16x4 v = *(const bf16x4*)&src[(size_t)(j0 + jj) * N_ + i0 + 4 * tx];
#pragma unroll
      for (int u = 0; u < 4; ++u) tile[jj][4 * tx + u] = (float)v[u];
    }
  }
  __syncthreads();
  // column partial sums over this block's 64 rows (j), per column i
  {
    const int cc = t & 63, g = t >> 6;  // 64 cols x 4 row-groups
    float s = 0.f;
#pragma unroll
    for (int r = 0; r < 16; ++r) s += tile[g * 16 + r][cc];
    red[g][cc] = s;
  }
  // transposed write
  bf16* dst = adjT + sb;
#pragma unroll
  for (int s = 0; s < 4; ++s) {
    const int ii = ty + 16 * s;
    bf16x4 o;
#pragma unroll
    for (int u = 0; u < 4; ++u) o[u] = (bf16)tile[4 * tx + u][ii];
    *(bf16x4*)&dst[(size_t)(i0 + ii) * N_ + j0 + 4 * tx] = o;
  }
  __syncthreads();
  if (t < 64)
    csp[((size_t)(j0 >> 6) * B_ + b) * N_ + i0 + t] =
        red[0][t] + red[1][t] + red[2][t] + red[3][t];
}

// degree scale r = colsum^-1/2 (0 if <=0), colsum = sum of 16 csp slices
__device__ __forceinline__ float rscale(const float* __restrict__ csp, int b, int node) {
  float c = 0.f;
#pragma unroll
  for (int z = 0; z < 16; ++z) c += csp[((size_t)z * B_ + b) * N_ + node];
  return c > 0.f ? rsqrtf(c) : 0.f;
}

// C[M][Nc] = A[M][K] * Bt[Nc][K]^T, with optional column scale (SCALEN:
// v *= r_n), row scale (SCALEM: v = r_m*v), bias, ReLU.  128x128 tile, BK=64,
// double-buffered LDS, raw s_barrier pipeline w/ fine-grained vmcnt.
// 1-D grid, XCD swizzle: id%8 = XCD, 2 batches per XCD, 32 tiles per batch.
template <int BIAS, int RELU, int OUTDYN, int SCALEN, int SCALEM, int GX>
__global__ __launch_bounds__(256)
void k_gemm_bt(const bf16* __restrict__ A, const bf16* __restrict__ Bt,
               const float* __restrict__ bias, void* __restrict__ C,
               const int* __restrict__ flag, const float* __restrict__ csp,
               int Nc, int K, long sA, long sB, long sC) {
  __shared__ __align__(16) char smem[65536];  // 2 x (As 16KB + Bs 16KB)
  const int id = blockIdx.x;
  const int xcd = id & 7, p = id >> 3;
  const int bz = xcd * 2 + (p >> 5);
  const int tl = p & 31;
  const int bx = tl % GX, by = tl / GX;

  const int tid = threadIdx.x;
  const int wid = tid >> 6, lane = tid & 63;
  const int wm = wid >> 1, wn = wid & 1;
  const int quad = lane >> 4, l16 = lane & 15;
  const int rl = lane >> 3;               // 0..7 staging row within 8-row issue
  const int cg8 = ((lane & 7) ^ rl) * 8;  // swizzled global col offset (elems)
  const int h = l16 & 7;                  // fragment-read swizzle key

  const bf16* gA = A + (size_t)bz * sA + (size_t)by * 128 * K;
  const bf16* gB = Bt + (size_t)bz * sB + (size_t)bx * 128 * K;

  f32x4 acc[4][4];
#pragma unroll
  for (int i = 0; i < 4; ++i)
#pragma unroll
    for (int j = 0; j < 4; ++j) acc[i][j] = (f32x4){0.f, 0.f, 0.f, 0.f};

  auto stage = [&](int d, int k0) {
    bf16* As = (bf16*)(smem + d * 32768);
    bf16* Bs = (bf16*)(smem + d * 32768 + 16384);
#pragma unroll
    for (int i = 0; i < 4; ++i) {
      const int r0 = wid * 32 + i * 8;  // wave-uniform LDS row base
      gld16(gA + (size_t)(r0 + rl) * K + k0 + cg8, &As[r0 * 64]);
      gld16(gB + (size_t)(r0 + rl) * K + k0 + cg8, &Bs[r0 * 64]);
    }
  };

  stage(0, 0);
  for (int k0 = 0; k0 < K; k0 += 64) {
    const int cur = (k0 >> 6) & 1;
    if (k0 + 64 < K) {
      stage(1 - cur, k0 + 64);
      asm volatile("s_waitcnt vmcnt(8)\n\ts_barrier" ::: "memory");
    } else {
      asm volatile("s_waitcnt vmcnt(0)\n\ts_barrier" ::: "memory");
    }
    const bf16* As = (const bf16*)(smem + cur * 32768);
    const bf16* Bs = (const bf16*)(smem + cur * 32768 + 16384);
#pragma unroll
    for (int s = 0; s < 2; ++s) {
      bf16x8 af[4], bfv[4];
#pragma unroll
      for (int tm = 0; tm < 4; ++tm)
        af[tm] = *(const bf16x8*)&As[(wm * 64 + tm * 16 + l16) * 64 +
                                     (((quad + 4 * s) ^ h) * 8)];
#pragma unroll
      for (int tn = 0; tn < 4; ++tn)
        bfv[tn] = *(const bf16x8*)&Bs[(wn * 64 + tn * 16 + l16) * 64 +
                                      (((quad + 4 * s) ^ h) * 8)];
#pragma unroll
      for (int tm = 0; tm < 4; ++tm)
#pragma unroll
        for (int tn = 0; tn < 4; ++tn)
          acc[tm][tn] =
              __builtin_amdgcn_mfma_f32_16x16x32_bf16(af[tm], bfv[tn], acc[tm][tn], 0, 0, 0);
    }
    asm volatile("s_barrier" ::: "memory");  // WAR protect (exec barrier only)
  }

  // per-block scale table (128 rows or cols) in LDS (K-loop LDS now free)
  float* rsh = (float*)(smem + 37376);  // repack region ends at 36864
  if (SCALEN || SCALEM) {
    if (tid < 128) {
      const int node = (SCALEM ? by * 128 : bx * 128) + tid;
      rsh[tid] = rscale(csp, bz, node);
    }
    __syncthreads();
  }

  // C/D layout: col = lane&15, row = quad*4 + reg  [m89/m91]
  const size_t cb = (size_t)bz * sC;
  const int mb_w = by * 128 + wm * 64;
  const int nb_w = bx * 128 + wn * 64;

  if (OUTDYN) {
    const int of32 = flag[0];
#pragma unroll
    for (int tn = 0; tn < 4; ++tn) {
      const int n = nb_w + tn * 16 + l16;
      float bv = BIAS ? bias[n] : 0.f;
      const float cscale = SCALEN ? rsh[wn * 64 + tn * 16 + l16] : 1.f;
#pragma unroll
      for (int tm = 0; tm < 4; ++tm) {
        const int m0 = mb_w + tm * 16 + quad * 4;
#pragma unroll
        for (int r = 0; r < 4; ++r) {
          float v = acc[tm][tn][r];
          if (SCALEM) v *= rsh[wm * 64 + tm * 16 + quad * 4 + r];
          if (SCALEN) v *= cscale;
          v += bv;
          if (RELU) v = v > 0.f ? v : 0.f;
          const size_t idx = cb + (size_t)(m0 + r) * Nc + n;
          if (of32) ((float*)C)[idx] = v;
          else      ((bf16*)C)[idx] = (bf16)v;
        }
      }
    }
  } else {
    // repack through per-wave LDS tile [64][72], then 16B coalesced stores
    bf16* W = (bf16*)smem + wid * (64 * 72);
#pragma unroll
    for (int tn = 0; tn < 4; ++tn) {
      const int n = nb_w + tn * 16 + l16;
      float bv = BIAS ? bias[n] : 0.f;
      const float cscale = SCALEN ? rsh[wn * 64 + tn * 16 + l16] : 1.f;
#pragma unroll
      for (int tm = 0; tm < 4; ++tm) {
#pragma unroll
        for (int r = 0; r < 4; ++r) {
          float v = acc[tm][tn][r];
          if (SCALEM) v *= rsh[wm * 64 + tm * 16 + quad * 4 + r];
          if (SCALEN) v *= cscale;
          v += bv;
          if (RELU) v = v > 0.f ? v : 0.f;
          W[(tm * 16 + quad * 4 + r) * 72 + tn * 16 + l16] = (bf16)v;
        }
      }
    }
    bf16* gC = (bf16*)C + cb;
#pragma unroll
    for (int i = 0; i < 8; ++i) {
      const int row = i * 8 + rl;
      bf16x8 v = *(const bf16x8*)&W[row * 72 + (lane & 7) * 8];
      *(bf16x8*)&gC[(size_t)(mb_w + row) * Nc + nb_w + (lane & 7) * 8] = v;
    }
  }
}

extern "C" void kernel_launch(void* const* d_in, const int* in_sizes, int n_in,
                              void* d_out, int out_size, void* d_ws, size_t ws_size,
                              hipStream_t stream) {
  // ws: csp(1MB) | flag | bc | adjT(32MB) | Wt(1.5MB) | Zt(16MB)  ~50.5MB
  char* ws = (char*)d_ws;
  float* csp  = (float*)ws;                         // 1 MB [16][B][N]
  int*  flag  = (int*)(ws + 1048576);
  float* bc   = (float*)(ws + 1048832);             // 6 KB [3][512]
  bf16* adjT  = (bf16*)(ws + 1056768);              // 32 MB [B][N][N]
  bf16* Wt    = (bf16*)(ws + 1056768 + 33554432);   // 1.5 MB [3][F][F]
  bf16* Zt    = (bf16*)(ws + 1056768 + 33554432 + 3 * F_ * F_ * 2);  // 16 MB
  bf16* Xc = (bf16*)d_out;  // d_out doubles as bf16 activation scratch

  const long sW = 0;
  const long sX = (long)N_ * F_;
  const long sZ = (long)F_ * N_;
  const long sAn = (long)N_ * N_;

  k_detect<<<1, 256, 0, stream>>>((const unsigned*)d_in[2], flag);
  k_prep<<<774 + (B_ * N_ * F_) / 1024, 256, 0, stream>>>(
      d_in[3], d_in[5], d_in[7], d_in[2], d_in[4], d_in[6], d_in[0], flag, bc, Wt, Xc);
  k_tran<<<dim3(N_ / 64, N_ / 64, B_), dim3(16, 16), 0, stream>>>(d_in[1], flag, adjT, csp);

  // GEMM1: Zt = Wt_z @ Xc^T, cols scaled by r_j   (M=F, Nc=N, K=F, GX=8)
  // GEMM2: X' = r_i * (adjT @ Zt^T) + b, ReLU     (M=N, Nc=F, K=N, GX=4)
  // layer 1
  k_gemm_bt<0, 0, 0, 1, 0, 8><<<512, 256, 0, stream>>>(Wt,               Xc, nullptr,   Zt, flag, csp, N_, F_, sW, sX, sZ);
  k_gemm_bt<1, 1, 0, 0, 1, 4><<<512, 256, 0, stream>>>(adjT,             Zt, bc,        Xc, flag, csp, F_, N_, sAn, sZ, sX);
  // layer 2
  k_gemm_bt<0, 0, 0, 1, 0, 8><<<512, 256, 0, stream>>>(Wt + F_ * F_,     Xc, nullptr,   Zt, flag, csp, N_, F_, sW, sX, sZ);
  k_gemm_bt<1, 1, 0, 0, 1, 4><<<512, 256, 0, stream>>>(adjT,             Zt, bc + 512,  Xc, flag, csp, F_, N_, sAn, sZ, sX);
  // layer 3
  k_gemm_bt<0, 0, 0, 1, 0, 8><<<512, 256, 0, stream>>>(Wt + 2 * F_ * F_, Xc, nullptr,   Zt, flag, csp, N_, F_, sW, sX, sZ);
  k_gemm_bt<1, 0, 1, 0, 1, 4><<<512, 256, 0, stream>>>(adjT,             Zt, bc + 1024, d_out, flag, csp, F_, N_, sAn, sZ, sX);
}